// Round 14
// baseline (875.960 us; speedup 1.0000x reference)
//
#include <hip/hip_runtime.h>

// PRNNLayer: B=4096 chains x T=2048 steps, 5 states.
// R16: R15 structure (one role per block, pins, SoA planes + 8ts-tx, no
// barriers/LDS/pre) + TWO CHAINS PER LANE, STATEMENT-INTERLEAVED.
// Rationale: R15's roles floor = ~38% issue / ~62% dependency stall (VALUBusy
// 9.4% of 25% ceiling). R9 proved the compiler won't interleave two
// sequentially-WRITTEN chain bodies; R16 pair-codes every statement
// (x0; x1; adjacent) so a ready independent instruction exists at each stall
// without any scheduler reordering. 128 blocks x 64 threads: role=blk&3,
// grp=blk>>2, chains bA=grp*128+lane, bB=bA+64 (every wave still alone on
// its CU -- R14's concentration regression avoided). CH=8, 2-chunk output
// accumulation -> 64B plane stores. All arithmetic verbatim.

#define NB 4096
#define NT 2048
#define CH 8
#define NCH (NT / CH)         // 256
#define BT ((size_t)NB * (size_t)NT)

#define L2E10 14.4269504089f  // 10*log2(e)  (hv(x) = sigmoid(10x))
#define L2E    1.44269504089f

__device__ __forceinline__ float rcpf(float x) { return __builtin_amdgcn_rcpf(x); }
__device__ __forceinline__ float ex2(float a)  { return __builtin_amdgcn_exp2f(a); }
__device__ __forceinline__ float ex2c(float a) { return __builtin_amdgcn_exp2f(fminf(a, 80.0f)); }
__device__ __forceinline__ float clip1e5(float x) {
    return __builtin_amdgcn_fmed3f(x, -100000.0f, 100000.0f);
}
__device__ __forceinline__ void pinbuf(const float* d, int n4) {
    const float4* v = (const float4*)d;
    #pragma unroll
    for (int i = 0; i < n4; ++i)
        asm volatile("" :: "v"(v[i].x), "v"(v[i].y), "v"(v[i].z), "v"(v[i].w));
}

__global__ __launch_bounds__(64, 1)
void prnn_roles(const float* __restrict__ inp, const float* __restrict__ theta,
                float* __restrict__ out, float* __restrict__ wsp, int use_ws) {
    const int lane = threadIdx.x;
    const int role = blockIdx.x & 3;
    const int b0 = (blockIdx.x >> 2) * 128 + lane;
    const int b1 = b0 + 64;

    const float f_     = theta[0] * 0.1f;
    const float smax_  = theta[1] * 1950.0f;
    const float qmax_  = theta[2] * 50.0f;
    const float ddf_   = theta[3] * 5.0f;
    const float tmin_  = theta[4] * -3.0f;
    const float tmax_  = theta[5] * 3.0f;
    const float Kc_    = theta[6] * 0.5f;
    const float SCmax_ = theta[7] * 1.5f;
    const float spmax_ = theta[8] * 1950.0f;
    const float qpmax_ = theta[9] * 40.0f;
    const float kp     = theta[10];
    const float sgmax_ = theta[11] * 1950.0f;
    const float qgmax_ = theta[12] * 40.0f;
    const float Kl_    = theta[13] * 0.5f;
    const float Kn_    = theta[14] * 0.5f;

    const float inv_smax = rcpf(smax_);
    const float KcDc  = Kc_ * 0.849932f;
    const float c_sn  = -L2E10 * tmin_;
    const float c_m   =  L2E10 * tmax_;
    const float c_dd  = -ddf_ * tmax_;
    const float c_sc1 =  L2E10 * SCmax_ * 1.4f;
    const float c_sc0 =  L2E10 * SCmax_ * 0.6f;
    const float c_2p  =  L2E10 * spmax_;
    const float c_3s  =  L2E10 * smax_;
    const float c_4s  =  L2E10 * sgmax_;
    const float fE    = f_ * L2E;
    const float c_E2  = -fE * spmax_;
    const float c_E3  = -fE * smax_;
    const float c_E4  = -fE * sgmax_;

    const float* ip0 = inp + (size_t)b0 * (NT * 3);
    const float* ip1 = inp + (size_t)b1 * (NT * 3);
    float*       op0 = out + (size_t)b0 * (NT * 5);
    float*       op1 = out + (size_t)b1 * (NT * 5);
    float* wbase = use_ws ? wsp : out;

    // 64B plane store (16 floats accumulated over 2 chunks)
    auto st16 = [&](float* plane, const float* ob, int off) {
        float4* d = (float4*)(plane + (size_t)off);
        const float4* s = (const float4*)ob;
        #pragma unroll
        for (int i = 0; i < 4; ++i) d[i] = s[i];
    };

    if (role == 0) {
        // ---- s0 x2 chains, statement-interleaved ----
        float sa = 0.f, sb = 0.f;
        float iA0[CH * 3], iA1[CH * 3], iB0[CH * 3], iB1[CH * 3];
        float oa[2 * CH], ob[2 * CH];
        float* w0a = wbase + 0 * BT + (size_t)b0 * NT;
        float* w0b = wbase + 0 * BT + (size_t)b1 * NT;
        auto pf = [&](float* d0, float* d1, int c) {
            const float4* s0 = (const float4*)(ip0 + (size_t)c * (CH * 3));
            const float4* s1 = (const float4*)(ip1 + (size_t)c * (CH * 3));
            #pragma unroll
            for (int i = 0; i < (CH * 3) / 4; ++i) {
                ((float4*)d0)[i] = s0[i];
                ((float4*)d1)[i] = s1[i];
            }
        };
        auto cw = [&](const float* d0, const float* d1, int half) {
            #pragma unroll
            for (int i = 0; i < CH; ++i) {
                const float p0 = d0[i * 3 + 0], p1 = d1[i * 3 + 0];
                const float dl0 = d0[i * 3 + 2], dl1 = d1[i * 3 + 2];
                const float dy0 = rcpf(1.0f + ex2(fmaf(-L2E10, dl0, 7.21347520f)));
                const float dy1 = rcpf(1.0f + ex2(fmaf(-L2E10, dl1, 7.21347520f)));
                const float da0 = 1.0f + ex2(fmaf(-L2E10, p0, L2E));
                const float da1 = 1.0f + ex2(fmaf(-L2E10, p1, L2E));
                const float la0 = fmaf(0.328f, dy0, 0.15f);
                const float la1 = fmaf(0.328f, dy1, 0.15f);
                const float kc0 = fmaf(0.6f, dy0, 0.4f);
                const float kc1 = fmaf(0.6f, dy1, 0.4f);
                const float kt0 = KcDc * kc0 * la0;
                const float kt1 = KcDc * kc1 * la1;
                const float zd0 = fmaf(c_sc1, dy0, c_sc0);
                const float zd1 = fmaf(c_sc1, dy1, c_sc0);
                const float e0a = ex2(-L2E10 * sa);
                const float e0b = ex2(-L2E10 * sb);
                const float ea  = ex2(fmaf(-L2E10, sa, zd0));
                const float eb  = ex2(fmaf(-L2E10, sb, zd1));
                const float d0a = 1.0f + e0a;
                const float d0b = 1.0f + e0b;
                const float dsa = 1.0f + ea;
                const float dsb = 1.0f + eb;
                const float Ra  = rcpf(da0 * d0a * dsa);
                const float Rb  = rcpf(da1 * d0b * dsb);
                const float pa  = Ra * fmaf(d0a * ea, kt0, p0);
                const float pb  = Rb * fmaf(d0b * eb, kt1, p1);
                sa += clip1e5(pa);
                sb += clip1e5(pb);
                oa[half * CH + i] = sa;
                ob[half * CH + i] = sb;
            }
        };
        pf(iA0, iA1, 0);
        for (int c = 0; c < NCH; c += 2) {
            pf(iB0, iB1, c + 1);
            pinbuf(iA0, (CH * 3) / 4); pinbuf(iA1, (CH * 3) / 4);
            cw(iA0, iA1, 0);
            if (c + 2 < NCH) pf(iA0, iA1, c + 2);
            pinbuf(iB0, (CH * 3) / 4); pinbuf(iB1, (CH * 3) / 4);
            cw(iB0, iB1, 1);
            if (use_ws) { st16(w0a, oa, c * CH); st16(w0b, ob, c * CH); }
            else {
                #pragma unroll
                for (int i = 0; i < 2 * CH; ++i) {
                    op0[(c * CH + i) * 5 + 0] = oa[i];
                    op1[(c * CH + i) * 5 + 0] = ob[i];
                }
            }
        }
    } else if (role == 1) {
        // ---- s1+s3 x2 chains, statement-interleaved (critical role) ----
        float s1a = 0.f, s1b = 0.f, s3a = 0.f, s3b = 0.f;
        float iA0[CH * 3], iA1[CH * 3], iB0[CH * 3], iB1[CH * 3];
        float o1a[2 * CH], o1b[2 * CH], o3a[2 * CH], o3b[2 * CH];
        float* w1a = wbase + 1 * BT + (size_t)b0 * NT;
        float* w1b = wbase + 1 * BT + (size_t)b1 * NT;
        float* w3a = wbase + 3 * BT + (size_t)b0 * NT;
        float* w3b = wbase + 3 * BT + (size_t)b1 * NT;
        auto pf = [&](float* d0, float* d1, int c) {
            const float4* s0 = (const float4*)(ip0 + (size_t)c * (CH * 3));
            const float4* s1 = (const float4*)(ip1 + (size_t)c * (CH * 3));
            #pragma unroll
            for (int i = 0; i < (CH * 3) / 4; ++i) {
                ((float4*)d0)[i] = s0[i];
                ((float4*)d1)[i] = s1[i];
            }
        };
        auto cw = [&](const float* d0, const float* d1, int half) {
            #pragma unroll
            for (int i = 0; i < CH; ++i) {
                const float p0 = d0[i * 3 + 0], p1 = d1[i * 3 + 0];
                const float t0 = d0[i * 3 + 1], t1 = d1[i * 3 + 1];
                const float l0 = d0[i * 3 + 2], l1 = d1[i * 3 + 2];
                const float A1a = t0 + 237.3f, A1b = t1 + 237.3f;
                const float A2a = t0 + 273.2f, A2b = t1 + 273.2f;
                const float qa = rcpf(A1a * A2a);
                const float qb = rcpf(A1b * A2b);
                const float pea = 436.98672f * l0 * ex2(24.958624f * t0 * (qa * A2a)) * (qa * A1a);
                const float peb = 436.98672f * l1 * ex2(24.958624f * t1 * (qb * A2b)) * (qb * A1b);
                const float psa = rcpf(1.0f + ex2(fmaf(L2E10, t0, c_sn))) * p0;
                const float psb = rcpf(1.0f + ex2(fmaf(L2E10, t1, c_sn))) * p1;
                const float dma = 1.0f + ex2(fmaf(-L2E10, t0, c_m));
                const float dmb = 1.0f + ex2(fmaf(-L2E10, t1, c_m));
                const float pra = p0 - psa;
                const float prb = p1 - psb;
                const float e1a = ex2(-L2E10 * s1a);
                const float e1b = ex2(-L2E10 * s1b);
                const float mla = rcpf(dma * (1.0f + e1a)) * fminf(s1a, fmaf(ddf_, t0, c_dd));
                const float mlb = rcpf(dmb * (1.0f + e1b)) * fminf(s1b, fmaf(ddf_, t1, c_dd));
                const float e3a = ex2(-L2E10 * s3a);
                const float e3b = ex2(-L2E10 * s3b);
                const float ga  = ex2c(fmaf(-L2E10, s3a, c_3s));
                const float gb  = ex2c(fmaf(-L2E10, s3b, c_3s));
                const float Ra  = rcpf((1.0f + e3a) * (1.0f + ga));
                const float Rb  = rcpf((1.0f + e3b) * (1.0f + gb));
                const float Ea  = ex2(fmaf(fE, s3a, c_E3));
                const float Eb  = ex2(fmaf(fE, s3b, c_E3));
                const float ta_ = pea * fmaf(ga * s3a, inv_smax, 1.0f);
                const float tb_ = peb * fmaf(gb * s3b, inv_smax, 1.0f);
                const float ua  = qmax_ * fmaf(ga, Ea, 1.0f);
                const float ub  = qmax_ * fmaf(gb, Eb, 1.0f);
                const float ofa = Ra * (ta_ + ua + (s3a - smax_));
                const float ofb = Rb * (tb_ + ub + (s3b - smax_));
                const float d3a = pra + mla - ofa;
                const float d3b = prb + mlb - ofb;
                s1a += clip1e5(psa - mla);
                s1b += clip1e5(psb - mlb);
                s3a += clip1e5(d3a);
                s3b += clip1e5(d3b);
                o1a[half * CH + i] = s1a;
                o1b[half * CH + i] = s1b;
                o3a[half * CH + i] = s3a;
                o3b[half * CH + i] = s3b;
            }
        };
        pf(iA0, iA1, 0);
        for (int c = 0; c < NCH; c += 2) {
            pf(iB0, iB1, c + 1);
            pinbuf(iA0, (CH * 3) / 4); pinbuf(iA1, (CH * 3) / 4);
            cw(iA0, iA1, 0);
            if (c + 2 < NCH) pf(iA0, iA1, c + 2);
            pinbuf(iB0, (CH * 3) / 4); pinbuf(iB1, (CH * 3) / 4);
            cw(iB0, iB1, 1);
            if (use_ws) {
                st16(w1a, o1a, c * CH); st16(w1b, o1b, c * CH);
                st16(w3a, o3a, c * CH); st16(w3b, o3b, c * CH);
            } else {
                #pragma unroll
                for (int i = 0; i < 2 * CH; ++i) {
                    op0[(c * CH + i) * 5 + 1] = o1a[i];
                    op1[(c * CH + i) * 5 + 1] = o1b[i];
                    op0[(c * CH + i) * 5 + 3] = o3a[i];
                    op1[(c * CH + i) * 5 + 3] = o3b[i];
                }
            }
        }
    } else if (role == 2) {
        // ---- s2 x2 chains, statement-interleaved ----
        float sa = 0.f, sb = 0.f;
        float pA0[CH], pA1[CH], pB0[CH], pB1[CH];
        float oa[2 * CH], ob[2 * CH];
        float* w2a = wbase + 2 * BT + (size_t)b0 * NT;
        float* w2b = wbase + 2 * BT + (size_t)b1 * NT;
        auto pf = [&](float* P0, float* P1, int c) {
            #pragma unroll
            for (int i = 0; i < CH; ++i) {
                P0[i] = ip0[(c * CH + i) * 3 + 0];
                P1[i] = ip1[(c * CH + i) * 3 + 0];
            }
        };
        auto cw = [&](const float* P0, const float* P1, int half) {
            #pragma unroll
            for (int i = 0; i < CH; ++i) {
                const float p0 = P0[i], p1 = P1[i];
                const float e2a = ex2(-L2E10 * sa);
                const float e2b = ex2(-L2E10 * sb);
                const float ga  = ex2c(fmaf(-L2E10, sa, c_2p));
                const float gb  = ex2c(fmaf(-L2E10, sb, c_2p));
                const float Ra  = rcpf((1.0f + e2a) * (1.0f + ga));
                const float Rb  = rcpf((1.0f + e2b) * (1.0f + gb));
                const float Ea  = ex2(fmaf(fE, sa, c_E2));
                const float Eb  = ex2(fmaf(fE, sb, c_E2));
                const float qa  = Ra * fmaf(ga * Ea, kp * p0, qpmax_);
                const float qb  = Rb * fmaf(gb * Eb, kp * p1, qpmax_);
                sa += clip1e5(qa);
                sb += clip1e5(qb);
                oa[half * CH + i] = sa;
                ob[half * CH + i] = sb;
            }
        };
        pf(pA0, pA1, 0);
        for (int c = 0; c < NCH; c += 2) {
            pf(pB0, pB1, c + 1);
            pinbuf(pA0, CH / 4); pinbuf(pA1, CH / 4);
            cw(pA0, pA1, 0);
            if (c + 2 < NCH) pf(pA0, pA1, c + 2);
            pinbuf(pB0, CH / 4); pinbuf(pB1, CH / 4);
            cw(pB0, pB1, 1);
            if (use_ws) { st16(w2a, oa, c * CH); st16(w2b, ob, c * CH); }
            else {
                #pragma unroll
                for (int i = 0; i < 2 * CH; ++i) {
                    op0[(c * CH + i) * 5 + 2] = oa[i];
                    op1[(c * CH + i) * 5 + 2] = ob[i];
                }
            }
        }
    } else {
        // ---- s4 x2 chains, statement-interleaved ----
        float sa = 0.f, sb = 0.f;
        float pA0[CH], pA1[CH], pB0[CH], pB1[CH];
        float oa[2 * CH], ob[2 * CH];
        float* w4a = wbase + 4 * BT + (size_t)b0 * NT;
        float* w4b = wbase + 4 * BT + (size_t)b1 * NT;
        auto pf = [&](float* P0, float* P1, int c) {
            #pragma unroll
            for (int i = 0; i < CH; ++i) {
                P0[i] = ip0[(c * CH + i) * 3 + 0];
                P1[i] = ip1[(c * CH + i) * 3 + 0];
            }
        };
        auto cw = [&](const float* P0, const float* P1, int half) {
            #pragma unroll
            for (int i = 0; i < CH; ++i) {
                const float p0 = P0[i], p1 = P1[i];
                const float e4a = ex2(-L2E10 * sa);
                const float e4b = ex2(-L2E10 * sb);
                const float ga  = ex2c(fmaf(-L2E10, sa, c_4s));
                const float gb  = ex2c(fmaf(-L2E10, sb, c_4s));
                const float Ra  = rcpf((1.0f + e4a) * (1.0f + ga));
                const float Rb  = rcpf((1.0f + e4b) * (1.0f + gb));
                const float Ea  = ex2(fmaf(fE, sa, c_E4));
                const float Eb  = ex2(fmaf(fE, sb, c_E4));
                const float pl0 = p0 * fmaf(p0, Kn_, Kl_);
                const float pl1 = p1 * fmaf(p1, Kn_, Kl_);
                const float qa  = Ra * fmaf(ga * Ea, pl0, qgmax_);
                const float qb  = Rb * fmaf(gb * Eb, pl1, qgmax_);
                sa += clip1e5(qa);
                sb += clip1e5(qb);
                oa[half * CH + i] = sa;
                ob[half * CH + i] = sb;
            }
        };
        pf(pA0, pA1, 0);
        for (int c = 0; c < NCH; c += 2) {
            pf(pB0, pB1, c + 1);
            pinbuf(pA0, CH / 4); pinbuf(pA1, CH / 4);
            cw(pA0, pA1, 0);
            if (c + 2 < NCH) pf(pA0, pA1, c + 2);
            pinbuf(pB0, CH / 4); pinbuf(pB1, CH / 4);
            cw(pB0, pB1, 1);
            if (use_ws) { st16(w4a, oa, c * CH); st16(w4b, ob, c * CH); }
            else {
                #pragma unroll
                for (int i = 0; i < 2 * CH; ++i) {
                    op0[(c * CH + i) * 5 + 4] = oa[i];
                    op1[(c * CH + i) * 5 + 4] = ob[i];
                }
            }
        }
    }
}

// ---- Pass 2: SoA planes -> AoS out. 8 timesteps per thread. ----
__global__ __launch_bounds__(256)
void tx_kernel(const float* __restrict__ wsp, float* __restrict__ out) {
    const size_t idx = (size_t)blockIdx.x * 256 + threadIdx.x;  // BT/8 threads
    const size_t b  = idx / (NT / 8);
    const size_t t0 = (idx % (NT / 8)) * 8;
    const float* base = wsp + b * NT + t0;
    float v[5][8];
    #pragma unroll
    for (int s = 0; s < 5; ++s) {
        *(float4*)&v[s][0] = *(const float4*)(base + s * BT);
        *(float4*)&v[s][4] = *(const float4*)(base + s * BT + 4);
    }
    float o[40];
    #pragma unroll
    for (int t = 0; t < 8; ++t)
        #pragma unroll
        for (int s = 0; s < 5; ++s) o[t * 5 + s] = v[s][t];
    float4* d = (float4*)(out + (b * NT + t0) * 5);
    const float4* sv = (const float4*)o;
    #pragma unroll
    for (int i = 0; i < 10; ++i) d[i] = sv[i];
}

extern "C" void kernel_launch(void* const* d_in, const int* in_sizes, int n_in,
                              void* d_out, int out_size, void* d_ws, size_t ws_size,
                              hipStream_t stream) {
    const float* inp   = (const float*)d_in[0];
    const float* theta = (const float*)d_in[1];
    float* out = (float*)d_out;
    float* wsp = (float*)d_ws;
    const int use_ws = (wsp != nullptr && ws_size >= 5 * sizeof(float) * BT) ? 1 : 0;
    // 4 roles x 32 groups (128 chains each: 64 lanes x 2 chains/lane)
    prnn_roles<<<4 * (NB / 128), 64, 0, stream>>>(inp, theta, out, wsp, use_ws);
    if (use_ws)
        tx_kernel<<<(int)(BT / 8 / 256), 256, 0, stream>>>(wsp, out);
}